// Round 8
// baseline (332.205 us; speedup 1.0000x reference)
//
#include <hip/hip_runtime.h>
#include <stdint.h>
#include <math.h>

#define N_NODES 50000
#define N_EDGES 800000
#define D 128
#define N_GRAPHS 16
#define ZP 264         // LDS z-tile row pitch in bf16 elems (264*2B=528B = 132 floats -> 16B-aligned rows)
#define TN 32          // nodes per step-block
#define PBLK 128       // nodes per pool block
#define PSL 16         // nodes per pool slice
#define ESTR 64        // ELL stride (entries/node); >= max in-degree (Poisson(16): P(>64) ~ 1e-19), clamped
#define HB_ELEMS ((size_t)N_NODES * D)

typedef __attribute__((ext_vector_type(8))) short bf16x8;   // 8 bf16 (4 VGPRs)
typedef __attribute__((ext_vector_type(4))) float f32x4;
typedef __attribute__((ext_vector_type(4))) unsigned int u32x4;

__device__ __forceinline__ float leaky(float y){ return y > 0.f ? y : 0.01f * y; }

// monotonic float->uint encoding for atomic max; 0 = "empty" marker
__device__ __forceinline__ unsigned fenc(float f){
    unsigned u = __float_as_uint(f);
    return (f >= 0.f) ? (u | 0x80000000u) : ~u;
}
__device__ __forceinline__ float fdec(unsigned e){
    return (e & 0x80000000u) ? __uint_as_float(e & 0x7fffffffu) : __uint_as_float(~e);
}

// bf16 pack/unpack (round-to-nearest-even)
__device__ __forceinline__ unsigned short f2bf(float f){
    unsigned u = __float_as_uint(f);
    u += 0x7fffu + ((u >> 16) & 1u);
    return (unsigned short)(u >> 16);
}
__device__ __forceinline__ unsigned pk2(float lo, float hi){
    return (unsigned)f2bf(lo) | ((unsigned)f2bf(hi) << 16);
}
__device__ __forceinline__ void maxbf8(float a[8], u32x4 v){
    a[0] = fmaxf(a[0], __uint_as_float(v[0] << 16)); a[1] = fmaxf(a[1], __uint_as_float(v[0] & 0xffff0000u));
    a[2] = fmaxf(a[2], __uint_as_float(v[1] << 16)); a[3] = fmaxf(a[3], __uint_as_float(v[1] & 0xffff0000u));
    a[4] = fmaxf(a[4], __uint_as_float(v[2] << 16)); a[5] = fmaxf(a[5], __uint_as_float(v[2] & 0xffff0000u));
    a[6] = fmaxf(a[6], __uint_as_float(v[3] << 16)); a[7] = fmaxf(a[7], __uint_as_float(v[3] & 0xffff0000u));
}
__device__ __forceinline__ float4 max4(float4 a, float4 b){
    float4 r;
    r.x = fmaxf(a.x, b.x); r.y = fmaxf(a.y, b.y);
    r.z = fmaxf(a.z, b.z); r.w = fmaxf(a.w, b.w);
    return r;
}

// ---------------- zero pass: deg + xg (contiguous) ----------------
__global__ __launch_bounds__(256) void k_zero(unsigned* __restrict__ p){
    int id = blockIdx.x * 256 + threadIdx.x;
    if (id < 50048 + N_GRAPHS * D) p[id] = 0u;
}

// ---------------- combined pre-pass: hb=bf16(x), Wt transpose, ELL fill (deg pre-zeroed) -------
// ELL fill spread across ALL 6250 blocks (tid<128 handles edge blockIdx*128+tid; 6250*128=800K):
// 2x the co-resident atomic chains vs R7's half-grid packing (R6->R7 showed fill time ~ 1/chains).
// The edge load + atomicAdd are issued BEFORE the conversion work in program order, so the
// ~500-800cy atomic-return latency hides under this thread's own float4 convert stream; the
// dependent 2B scatter store is fire-and-forget (only the end-of-kernel vmcnt drain waits).
// deg doubles as the fill cursor.
__global__ __launch_bounds__(256) void k_pre(const float* __restrict__ x, unsigned short* __restrict__ hb,
                                             const float* __restrict__ w0, const float* __restrict__ w1,
                                             const float* __restrict__ w2, const float* __restrict__ w3,
                                             unsigned short* __restrict__ Wt,
                                             const int* __restrict__ src, const int* __restrict__ dst,
                                             int* __restrict__ deg, unsigned short* __restrict__ ell){
    int tid = threadIdx.x;
    int id = blockIdx.x * 256 + tid;

    // ---- fill issue (early): load edge, start atomic ----
    int e = blockIdx.x * 128 + tid;          // valid when tid < 128
    int fill = (tid < 128) && (e < N_EDGES);
    int d = 0, s = 0, p = ESTR;
    if (fill){
        d = dst[e];
        s = src[e];
        p = atomicAdd(&deg[d], 1);           // latency overlaps the conversion below
    }

    // ---- streaming conversion work ----
    if (id < N_NODES * D / 4){
        float4 v = ((const float4*)x)[id];
        uint2 r; r.x = pk2(v.x, v.y); r.y = pk2(v.z, v.w);
        ((uint2*)hb)[id] = r;
    }
    if (id < 4 * D * 2 * D){
        int layer = id >> 15;
        int rem = id & 32767;
        int n = rem >> 8;
        int k = rem & 255;
        const float* w = (layer == 0) ? w0 : (layer == 1) ? w1 : (layer == 2) ? w2 : w3;
        Wt[id] = f2bf(w[(size_t)k * D + n]);
    }

    // ---- fill commit (late): consume atomic result ----
    if (fill && p < ESTR) ell[(size_t)d * ESTR + p] = (unsigned short)s;
}

// ---------------- pad each ELL row to a multiple of 8 (duplicate first edge, max-invariant) ----
// Also clamps deg to ESTR (overflow guard; unreachable for this dataset's degree distribution).
__global__ __launch_bounds__(256) void k_padell(int* __restrict__ deg, unsigned short* __restrict__ ell){
    int i = blockIdx.x * 256 + threadIdx.x;
    if (i < N_NODES){
        int n = deg[i];
        if (n > ESTR){ n = ESTR; deg[i] = ESTR; }
        if (n > 0){
            int n8 = (n + 7) & ~7;
            if (n8 > n){
                unsigned short s0 = ell[(size_t)i * ESTR];
                for (int j = n; j < n8; j++) ell[(size_t)i * ESTR + j] = s0;
            }
        }
    }
}

// ---------------- f32 -> bf16 shadow convert (fallback path) ----------------
__global__ __launch_bounds__(256) void k_cvt(const float* __restrict__ src, unsigned short* __restrict__ dst){
    int id = blockIdx.x * 256 + threadIdx.x;
    if (id < N_NODES * D / 4){
        float4 v = ((const float4*)src)[id];
        uint2 r; r.x = pk2(v.x, v.y); r.y = pk2(v.z, v.w);
        ((uint2*)dst)[id] = r;
    }
}

// ---------------- fused step: 32-node tile, 256 threads (4 waves), ELL gather ------------------
// R3 structure (best measured: 43.9us): wave w computes BOTH 16-row m-tiles for feature slice
// f0=w*32 (B-frags loaded once, used twice -> 2KB/node weight traffic). Gather: one node per
// 16-lane group, MLP=8 with empty-asm liveness barrier, tail-free via 8-padded ELL rows.
// No perm/off indirection: node = blockIdx*TN + row; ELL base = node*ESTR.
__global__ __launch_bounds__(256, 8) void k_step(const float* __restrict__ hin,
                                              const unsigned short* __restrict__ hb,
                                              const unsigned short* __restrict__ ell,
                                              const int* __restrict__ deg,
                                              const unsigned short* __restrict__ Wt, const float* __restrict__ b,
                                              float* __restrict__ hout, unsigned short* __restrict__ hbout,
                                              int add_skip, int write_hb){
    __shared__ unsigned short zt[TN * ZP];    // 32 rows x 528B = 16896B
    int tid = threadIdx.x;
    int nb = (int)blockIdx.x * TN;
    int lane = tid & 63;
    int wv = tid >> 6;                    // 0..3

    // stage h-half: 512 slots = 32 rows x 16 chunks; 256 threads x 2
    #pragma unroll
    for (int j = 0; j < 2; j++){
        int idx = j * 256 + tid;
        int row = idx >> 4;               // 0..31
        int ch  = idx & 15;               // 16B chunk -> feats ch*8..+7
        int node = nb + row;
        uint4 v = make_uint4(0u, 0u, 0u, 0u);
        if (node < N_NODES) v = *(const uint4*)&hb[(size_t)node * D + ch * 8];
        *(uint4*)&zt[row * ZP + ch * 8] = v;
    }

    // gather-max: one node per 16-lane group, 2 passes of 16 nodes; MLP=8, id-prefetch,
    // tail-free (8-padded ELL). Empty-asm barrier keeps all 8 loads live (8-deep MLP).
    #pragma unroll 1
    for (int pass = 0; pass < 2; pass++){
        int group = pass * 16 + (tid >> 4);   // 0..31 == node row
        int chunk = tid & 15;                 // feats chunk*8..+7
        int node = nb + group;
        int n = 0;
        if (node < N_NODES) n = deg[node];
        size_t base = (size_t)node * ESTR;
        const float NEG = -INFINITY;
        float a[8] = {NEG, NEG, NEG, NEG, NEG, NEG, NEG, NEG};
        int n8 = (n + 7) & ~7;            // 0 when n==0
        if (n8 > 0){
            uint4 ss = *(const uint4*)&ell[base];         // 8 edge ids, 16B-aligned
            for (int i = 0; i < n8; i += 8){
                uint4 sc = ss;
                if (i + 8 < n8) ss = *(const uint4*)&ell[base + i + 8];   // prefetch next ids
                int s0 = sc.x & 0xffff, s1 = sc.x >> 16;
                int s2 = sc.y & 0xffff, s3 = sc.y >> 16;
                int s4 = sc.z & 0xffff, s5 = sc.z >> 16;
                int s6 = sc.w & 0xffff, s7 = sc.w >> 16;
                u32x4 v0 = *(const u32x4*)&hb[(size_t)s0 * D + chunk * 8];
                u32x4 v1 = *(const u32x4*)&hb[(size_t)s1 * D + chunk * 8];
                u32x4 v2 = *(const u32x4*)&hb[(size_t)s2 * D + chunk * 8];
                u32x4 v3 = *(const u32x4*)&hb[(size_t)s3 * D + chunk * 8];
                u32x4 v4 = *(const u32x4*)&hb[(size_t)s4 * D + chunk * 8];
                u32x4 v5 = *(const u32x4*)&hb[(size_t)s5 * D + chunk * 8];
                u32x4 v6 = *(const u32x4*)&hb[(size_t)s6 * D + chunk * 8];
                u32x4 v7 = *(const u32x4*)&hb[(size_t)s7 * D + chunk * 8];
                asm volatile("" : "+v"(v0), "+v"(v1), "+v"(v2), "+v"(v3),
                                  "+v"(v4), "+v"(v5), "+v"(v6), "+v"(v7));
                maxbf8(a, v0); maxbf8(a, v1); maxbf8(a, v2); maxbf8(a, v3);
                maxbf8(a, v4); maxbf8(a, v5); maxbf8(a, v6); maxbf8(a, v7);
            }
        }
        uint4 r;
        if (n == 0){
            r = make_uint4(0u, 0u, 0u, 0u);
        } else {
            r.x = pk2(a[0], a[1]); r.y = pk2(a[2], a[3]);
            r.z = pk2(a[4], a[5]); r.w = pk2(a[6], a[7]);
        }
        *(uint4*)&zt[group * ZP + D + chunk * 8] = r;
    }
    __syncthreads();

    // MFMA: wave w -> feature slice f0=w*32 (2 nt), BOTH m-tiles (rows 0..15, 16..31).
    // B-frags (global Wt, L2-resident) loaded once per (nt,ks), reused across both m-tiles.
    int col = lane & 15;
    int quad = lane >> 4;
    int f0 = wv * 32;

    f32x4 acc[2][2];
    acc[0][0] = (f32x4){0.f, 0.f, 0.f, 0.f};
    acc[0][1] = (f32x4){0.f, 0.f, 0.f, 0.f};
    acc[1][0] = (f32x4){0.f, 0.f, 0.f, 0.f};
    acc[1][1] = (f32x4){0.f, 0.f, 0.f, 0.f};

    const unsigned short* z0 = &zt[(col) * ZP + quad * 8];
    const unsigned short* z1 = &zt[(16 + col) * ZP + quad * 8];
    const unsigned short* wrow = &Wt[(size_t)(f0 + col) * 256 + quad * 8];

    #pragma unroll
    for (int ks = 0; ks < 8; ks++){
        bf16x8 b0 = *(const bf16x8*)&wrow[ks * 32];
        bf16x8 b1 = *(const bf16x8*)&wrow[16 * 256 + ks * 32];
        bf16x8 a0 = *(const bf16x8*)&z0[ks * 32];
        bf16x8 a1 = *(const bf16x8*)&z1[ks * 32];
        acc[0][0] = __builtin_amdgcn_mfma_f32_16x16x32_bf16(a0, b0, acc[0][0], 0, 0, 0);
        acc[0][1] = __builtin_amdgcn_mfma_f32_16x16x32_bf16(a0, b1, acc[0][1], 0, 0, 0);
        acc[1][0] = __builtin_amdgcn_mfma_f32_16x16x32_bf16(a1, b0, acc[1][0], 0, 0, 0);
        acc[1][1] = __builtin_amdgcn_mfma_f32_16x16x32_bf16(a1, b1, acc[1][1], 0, 0, 0);
    }

    __syncthreads();   // all waves done reading zt (A-frags)

    // write y = leaky(acc + b) into zt as f32 (pitch 132 floats = 528 B)
    float* zf = (float*)zt;
    #pragma unroll
    for (int nt = 0; nt < 2; nt++){
        int feat = f0 + nt * 16 + col;
        float bb_ = b[feat];
        #pragma unroll
        for (int mt = 0; mt < 2; mt++){
            #pragma unroll
            for (int r = 0; r < 4; r++){
                int row = mt * 16 + quad * 4 + r;
                zf[row * 132 + feat] = leaky(acc[mt][nt][r] + bb_);
            }
        }
    }
    __syncthreads();

    // coalesced epilogue: 1024 float4 slots = 32 rows x 32 quads; 256 threads x 4
    #pragma unroll
    for (int j = 0; j < 4; j++){
        int idx = j * 256 + tid;
        int row = idx >> 5;               // 0..31
        int q = idx & 31;                 // feats 4q..4q+3
        int node = nb + row;
        if (node < N_NODES){
            float4 y = *(float4*)&zf[row * 132 + 4 * q];
            if (add_skip){
                float4 hv = *(const float4*)&hin[(size_t)node * D + 4 * q];
                y.x += hv.x; y.y += hv.y; y.z += hv.z; y.w += hv.w;
            }
            *(float4*)&hout[(size_t)node * D + 4 * q] = y;
            if (write_hb){
                ushort4 rb;
                rb.x = f2bf(y.x); rb.y = f2bf(y.y); rb.z = f2bf(y.z); rb.w = f2bf(y.w);
                *(ushort4*)&hbout[(size_t)node * D + 4 * q] = rb;
            }
        }
    }
}

// ---------------- global max-pool per graph (batch sorted, int32) ----------------
__global__ __launch_bounds__(256) void k_pool(const float* __restrict__ h, const int* __restrict__ batch,
                                              unsigned* __restrict__ xg){
    __shared__ unsigned lmax[2 * D];
    int tid = threadIdx.x;
    lmax[tid] = 0u;
    __syncthreads();

    int n0 = blockIdx.x * PBLK;
    int g0 = batch[n0];
    int q = tid & 31;
    int s = tid >> 5;
    int i0 = n0 + s * PSL;
    int i1 = min(i0 + PSL, N_NODES);

    if (i0 < N_NODES){
        const float NEG = -INFINITY;
        float4 m = make_float4(NEG, NEG, NEG, NEG);
        int curg = batch[i0];
        int i = i0;
        for (; i + 2 <= i1; i += 2){
            int ga = batch[i];
            int gb = batch[i + 1];
            float4 va = *(const float4*)&h[(size_t)i * D + 4 * q];
            float4 vb = *(const float4*)&h[(size_t)(i + 1) * D + 4 * q];
            if (ga != curg){
                int rel = curg - g0;
                unsigned* dst = (rel < 2) ? &lmax[rel * D + 4 * q] : &xg[curg * D + 4 * q];
                atomicMax(dst + 0, fenc(m.x)); atomicMax(dst + 1, fenc(m.y));
                atomicMax(dst + 2, fenc(m.z)); atomicMax(dst + 3, fenc(m.w));
                curg = ga; m = make_float4(NEG, NEG, NEG, NEG);
            }
            m = max4(m, va);
            if (gb != curg){
                int rel = curg - g0;
                unsigned* dst = (rel < 2) ? &lmax[rel * D + 4 * q] : &xg[curg * D + 4 * q];
                atomicMax(dst + 0, fenc(m.x)); atomicMax(dst + 1, fenc(m.y));
                atomicMax(dst + 2, fenc(m.z)); atomicMax(dst + 3, fenc(m.w));
                curg = gb; m = make_float4(NEG, NEG, NEG, NEG);
            }
            m = max4(m, vb);
        }
        if (i < i1){
            int ga = batch[i];
            float4 va = *(const float4*)&h[(size_t)i * D + 4 * q];
            if (ga != curg){
                int rel = curg - g0;
                unsigned* dst = (rel < 2) ? &lmax[rel * D + 4 * q] : &xg[curg * D + 4 * q];
                atomicMax(dst + 0, fenc(m.x)); atomicMax(dst + 1, fenc(m.y));
                atomicMax(dst + 2, fenc(m.z)); atomicMax(dst + 3, fenc(m.w));
                curg = ga; m = make_float4(NEG, NEG, NEG, NEG);
            }
            m = max4(m, va);
        }
        {
            int rel = curg - g0;
            unsigned* dst = (rel < 2) ? &lmax[rel * D + 4 * q] : &xg[curg * D + 4 * q];
            atomicMax(dst + 0, fenc(m.x)); atomicMax(dst + 1, fenc(m.y));
            atomicMax(dst + 2, fenc(m.z)); atomicMax(dst + 3, fenc(m.w));
        }
    }
    __syncthreads();

    if (tid < D){
        unsigned e = lmax[tid];
        if (e) atomicMax(&xg[g0 * D + tid], e);
    } else {
        int f = tid - D;
        int g1 = g0 + 1;
        if (g1 < N_GRAPHS){
            unsigned e = lmax[D + f];
            if (e) atomicMax(&xg[g1 * D + f], e);
        }
    }
}

// ---------------- head: leaky(xg @ wg[:128] + bg) ----------------
__global__ __launch_bounds__(256) void k_final(const unsigned* __restrict__ xg_enc, const float* __restrict__ wg,
                                               const float* __restrict__ bg, float* __restrict__ out){
    __shared__ float xs[N_GRAPHS * D];
    int tid = threadIdx.x;
    for (int i = tid; i < N_GRAPHS * D; i += 256){
        unsigned e = xg_enc[i];
        xs[i] = (e == 0u) ? 0.f : fdec(e);
    }
    __syncthreads();
    int g = tid >> 4;
    int j0 = (tid & 15) * 8;
    float acc[8];
    #pragma unroll
    for (int j = 0; j < 8; j++) acc[j] = 0.f;
    for (int k = 0; k < D; k++){
        float xv = xs[g * D + k];
        const float* wr = &wg[(size_t)k * D + j0];
        #pragma unroll
        for (int j = 0; j < 8; j++) acc[j] = fmaf(xv, wr[j], acc[j]);
    }
    float* orow = &out[(size_t)N_NODES * D + g * D + j0];
    #pragma unroll
    for (int j = 0; j < 8; j++) orow[j] = leaky(acc[j] + bg[j0 + j]);
}

extern "C" void kernel_launch(void* const* d_in, const int* in_sizes, int n_in,
                              void* d_out, int out_size, void* d_ws, size_t ws_size,
                              hipStream_t stream){
    const float* x = (const float*)d_in[0];
    const int* eidx  = (const int*)d_in[1];   // harness converts integer inputs to int32
    const int* batch = (const int*)d_in[2];
    const float* w[4]  = {(const float*)d_in[4], (const float*)d_in[6], (const float*)d_in[8], (const float*)d_in[10]};
    const float* bb[4] = {(const float*)d_in[5], (const float*)d_in[7], (const float*)d_in[9], (const float*)d_in[11]};
    const float* wg = (const float*)d_in[12];
    const float* bg = (const float*)d_in[13];
    const int* esrc = eidx;
    const int* edst = eidx + N_EDGES;

    // workspace layout: deg+xg (zeroed together) + Wt + ELL (6.4MB) + hb0 (+hb1 if ping-pong fits)
    char* ws = (char*)d_ws;
    int* deg    = (int*)ws;       ws += 50048 * 4;
    unsigned* xg_enc = (unsigned*)ws; ws += N_GRAPHS * D * 4;   // contiguous with deg for k_zero
    unsigned short* Wt = (unsigned short*)ws; ws += 4 * 2 * D * D * 2;  // 4 layers, [n][k] bf16
    unsigned short* ell = (unsigned short*)ws; ws += (size_t)N_NODES * ESTR * 2;
    unsigned short* hb0 = (unsigned short*)(((uintptr_t)ws + 255) & ~(uintptr_t)255);
    unsigned short* hb1 = hb0 + HB_ELEMS;
    size_t need_pp = (size_t)((char*)(hb1 + HB_ELEMS) - (char*)d_ws);
    int pp = (ws_size >= need_pp);     // ping-pong shadow if workspace allows (deterministic per run)
    float* h = (float*)d_out;          // f32 h lives in the output buffer (fully written by step 0)

    k_zero  <<<204, 256, 0, stream>>>((unsigned*)deg);
    k_pre   <<<6250, 256, 0, stream>>>(x, hb0, w[0], w[1], w[2], w[3], Wt, esrc, edst, deg, ell);
    k_padell<<<196, 256, 0, stream>>>(deg, ell);

    unsigned short* cur = hb0;
    unsigned short* nxt = pp ? hb1 : hb0;
    for (int s = 0; s < 4; s++){
        int wb = pp && (s < 3);        // ping-pong: write next shadow in-kernel (separate buffer)
        k_step<<<(N_NODES + TN - 1) / TN, 256, 0, stream>>>(h, cur, ell, deg,
                                                        Wt + (size_t)s * 2 * D * D, bb[s], h, nxt,
                                                        s > 0, wb);
        if (!pp && s < 3)              // fallback: refresh single shadow in a separate launch
            k_cvt<<<6250, 256, 0, stream>>>(h, hb0);
        if (pp){ unsigned short* t = cur; cur = nxt; nxt = t; }
    }

    k_pool <<<(N_NODES + PBLK - 1) / PBLK, 256, 0, stream>>>(h, batch, xg_enc);
    k_final<<<1, 256, 0, stream>>>(xg_enc, wg, bg, (float*)d_out);
}

// Round 9
// 328.294 us; speedup vs baseline: 1.0119x; 1.0119x over previous
//
#include <hip/hip_runtime.h>
#include <stdint.h>
#include <math.h>

#define N_NODES 50000
#define N_EDGES 800000
#define D 128
#define N_GRAPHS 16
#define ZP 264         // LDS z-tile row pitch in bf16 elems (264*2B=528B = 132 floats -> 16B-aligned rows)
#define TN 32          // nodes per step-block
#define PBLK 128       // nodes per pool block
#define PSL 16         // nodes per pool slice
#define ESTR 64        // ELL stride (entries/node); >= max in-degree (Poisson(16): P(>64) ~ 1e-19), clamped
#define DEGP 16        // deg padding: one counter per 64B cache line (line-lock contention probe)
#define HB_ELEMS ((size_t)N_NODES * D)

typedef __attribute__((ext_vector_type(8))) short bf16x8;   // 8 bf16 (4 VGPRs)
typedef __attribute__((ext_vector_type(4))) float f32x4;
typedef __attribute__((ext_vector_type(4))) unsigned int u32x4;

__device__ __forceinline__ float leaky(float y){ return y > 0.f ? y : 0.01f * y; }

// monotonic float->uint encoding for atomic max; 0 = "empty" marker
__device__ __forceinline__ unsigned fenc(float f){
    unsigned u = __float_as_uint(f);
    return (f >= 0.f) ? (u | 0x80000000u) : ~u;
}
__device__ __forceinline__ float fdec(unsigned e){
    return (e & 0x80000000u) ? __uint_as_float(e & 0x7fffffffu) : __uint_as_float(~e);
}

// bf16 pack/unpack (round-to-nearest-even)
__device__ __forceinline__ unsigned short f2bf(float f){
    unsigned u = __float_as_uint(f);
    u += 0x7fffu + ((u >> 16) & 1u);
    return (unsigned short)(u >> 16);
}
__device__ __forceinline__ unsigned pk2(float lo, float hi){
    return (unsigned)f2bf(lo) | ((unsigned)f2bf(hi) << 16);
}
__device__ __forceinline__ void maxbf8(float a[8], u32x4 v){
    a[0] = fmaxf(a[0], __uint_as_float(v[0] << 16)); a[1] = fmaxf(a[1], __uint_as_float(v[0] & 0xffff0000u));
    a[2] = fmaxf(a[2], __uint_as_float(v[1] << 16)); a[3] = fmaxf(a[3], __uint_as_float(v[1] & 0xffff0000u));
    a[4] = fmaxf(a[4], __uint_as_float(v[2] << 16)); a[5] = fmaxf(a[5], __uint_as_float(v[2] & 0xffff0000u));
    a[6] = fmaxf(a[6], __uint_as_float(v[3] << 16)); a[7] = fmaxf(a[7], __uint_as_float(v[3] & 0xffff0000u));
}
__device__ __forceinline__ float4 max4(float4 a, float4 b){
    float4 r;
    r.x = fmaxf(a.x, b.x); r.y = fmaxf(a.y, b.y);
    r.z = fmaxf(a.z, b.z); r.w = fmaxf(a.w, b.w);
    return r;
}

// ---------------- zero pass: padded deg + xg (contiguous) ----------------
__global__ __launch_bounds__(256) void k_zero(unsigned* __restrict__ p){
    int id = blockIdx.x * 256 + threadIdx.x;
    if (id < 50048 * DEGP + N_GRAPHS * D) p[id] = 0u;
}

// ---------------- combined pre-pass: hb=bf16(x), Wt transpose, ELL fill (deg pre-zeroed) -------
// ELL fill: R7 shape (best measured 47.5us): one edge per thread, packed in the first 3125
// blocks, atomic after the streaming code. NEW: deg counters padded to one per 64B line
// (deg[d*DEGP]) -- discriminates line-lock vs per-address serialization at the atomic unit.
// deg doubles as the fill cursor.
__global__ __launch_bounds__(256) void k_pre(const float* __restrict__ x, unsigned short* __restrict__ hb,
                                             const float* __restrict__ w0, const float* __restrict__ w1,
                                             const float* __restrict__ w2, const float* __restrict__ w3,
                                             unsigned short* __restrict__ Wt,
                                             const int* __restrict__ src, const int* __restrict__ dst,
                                             int* __restrict__ deg, unsigned short* __restrict__ ell){
    int id = blockIdx.x * 256 + threadIdx.x;
    if (id < N_NODES * D / 4){
        float4 v = ((const float4*)x)[id];
        uint2 r; r.x = pk2(v.x, v.y); r.y = pk2(v.z, v.w);
        ((uint2*)hb)[id] = r;
    }
    if (id < 4 * D * 2 * D){
        int layer = id >> 15;
        int rem = id & 32767;
        int n = rem >> 8;
        int k = rem & 255;
        const float* w = (layer == 0) ? w0 : (layer == 1) ? w1 : (layer == 2) ? w2 : w3;
        Wt[id] = f2bf(w[(size_t)k * D + n]);
    }
    if (id < N_EDGES){
        int d = dst[id];
        int s = src[id];
        int p = atomicAdd(&deg[d * DEGP], 1);
        if (p < ESTR) ell[(size_t)d * ESTR + p] = (unsigned short)s;
    }
}

// ---------------- pad each ELL row to a multiple of 8 (duplicate first edge, max-invariant) ----
// Also clamps deg to ESTR (overflow guard; unreachable for this dataset's degree distribution).
__global__ __launch_bounds__(256) void k_padell(int* __restrict__ deg, unsigned short* __restrict__ ell){
    int i = blockIdx.x * 256 + threadIdx.x;
    if (i < N_NODES){
        int n = deg[i * DEGP];
        if (n > ESTR){ n = ESTR; deg[i * DEGP] = ESTR; }
        if (n > 0){
            int n8 = (n + 7) & ~7;
            if (n8 > n){
                unsigned short s0 = ell[(size_t)i * ESTR];
                for (int j = n; j < n8; j++) ell[(size_t)i * ESTR + j] = s0;
            }
        }
    }
}

// ---------------- f32 -> bf16 shadow convert (fallback path) ----------------
__global__ __launch_bounds__(256) void k_cvt(const float* __restrict__ src, unsigned short* __restrict__ dst){
    int id = blockIdx.x * 256 + threadIdx.x;
    if (id < N_NODES * D / 4){
        float4 v = ((const float4*)src)[id];
        uint2 r; r.x = pk2(v.x, v.y); r.y = pk2(v.z, v.w);
        ((uint2*)dst)[id] = r;
    }
}

// ---------------- fused step: 32-node tile, 256 threads (4 waves), ELL gather ------------------
// R3 structure (best measured: 43.9us): wave w computes BOTH 16-row m-tiles for feature slice
// f0=w*32 (B-frags loaded once, used twice -> 2KB/node weight traffic). Gather: one node per
// 16-lane group, MLP=8 with empty-asm liveness barrier, tail-free via 8-padded ELL rows.
// No perm/off indirection: node = blockIdx*TN + row; ELL base = node*ESTR.
__global__ __launch_bounds__(256, 8) void k_step(const float* __restrict__ hin,
                                              const unsigned short* __restrict__ hb,
                                              const unsigned short* __restrict__ ell,
                                              const int* __restrict__ deg,
                                              const unsigned short* __restrict__ Wt, const float* __restrict__ b,
                                              float* __restrict__ hout, unsigned short* __restrict__ hbout,
                                              int add_skip, int write_hb){
    __shared__ unsigned short zt[TN * ZP];    // 32 rows x 528B = 16896B
    int tid = threadIdx.x;
    int nb = (int)blockIdx.x * TN;
    int lane = tid & 63;
    int wv = tid >> 6;                    // 0..3

    // stage h-half: 512 slots = 32 rows x 16 chunks; 256 threads x 2
    #pragma unroll
    for (int j = 0; j < 2; j++){
        int idx = j * 256 + tid;
        int row = idx >> 4;               // 0..31
        int ch  = idx & 15;               // 16B chunk -> feats ch*8..+7
        int node = nb + row;
        uint4 v = make_uint4(0u, 0u, 0u, 0u);
        if (node < N_NODES) v = *(const uint4*)&hb[(size_t)node * D + ch * 8];
        *(uint4*)&zt[row * ZP + ch * 8] = v;
    }

    // gather-max: one node per 16-lane group, 2 passes of 16 nodes; MLP=8, id-prefetch,
    // tail-free (8-padded ELL). Empty-asm barrier keeps all 8 loads live (8-deep MLP).
    #pragma unroll 1
    for (int pass = 0; pass < 2; pass++){
        int group = pass * 16 + (tid >> 4);   // 0..31 == node row
        int chunk = tid & 15;                 // feats chunk*8..+7
        int node = nb + group;
        int n = 0;
        if (node < N_NODES) n = deg[node * DEGP];
        size_t base = (size_t)node * ESTR;
        const float NEG = -INFINITY;
        float a[8] = {NEG, NEG, NEG, NEG, NEG, NEG, NEG, NEG};
        int n8 = (n + 7) & ~7;            // 0 when n==0
        if (n8 > 0){
            uint4 ss = *(const uint4*)&ell[base];         // 8 edge ids, 16B-aligned
            for (int i = 0; i < n8; i += 8){
                uint4 sc = ss;
                if (i + 8 < n8) ss = *(const uint4*)&ell[base + i + 8];   // prefetch next ids
                int s0 = sc.x & 0xffff, s1 = sc.x >> 16;
                int s2 = sc.y & 0xffff, s3 = sc.y >> 16;
                int s4 = sc.z & 0xffff, s5 = sc.z >> 16;
                int s6 = sc.w & 0xffff, s7 = sc.w >> 16;
                u32x4 v0 = *(const u32x4*)&hb[(size_t)s0 * D + chunk * 8];
                u32x4 v1 = *(const u32x4*)&hb[(size_t)s1 * D + chunk * 8];
                u32x4 v2 = *(const u32x4*)&hb[(size_t)s2 * D + chunk * 8];
                u32x4 v3 = *(const u32x4*)&hb[(size_t)s3 * D + chunk * 8];
                u32x4 v4 = *(const u32x4*)&hb[(size_t)s4 * D + chunk * 8];
                u32x4 v5 = *(const u32x4*)&hb[(size_t)s5 * D + chunk * 8];
                u32x4 v6 = *(const u32x4*)&hb[(size_t)s6 * D + chunk * 8];
                u32x4 v7 = *(const u32x4*)&hb[(size_t)s7 * D + chunk * 8];
                asm volatile("" : "+v"(v0), "+v"(v1), "+v"(v2), "+v"(v3),
                                  "+v"(v4), "+v"(v5), "+v"(v6), "+v"(v7));
                maxbf8(a, v0); maxbf8(a, v1); maxbf8(a, v2); maxbf8(a, v3);
                maxbf8(a, v4); maxbf8(a, v5); maxbf8(a, v6); maxbf8(a, v7);
            }
        }
        uint4 r;
        if (n == 0){
            r = make_uint4(0u, 0u, 0u, 0u);
        } else {
            r.x = pk2(a[0], a[1]); r.y = pk2(a[2], a[3]);
            r.z = pk2(a[4], a[5]); r.w = pk2(a[6], a[7]);
        }
        *(uint4*)&zt[group * ZP + D + chunk * 8] = r;
    }
    __syncthreads();

    // MFMA: wave w -> feature slice f0=w*32 (2 nt), BOTH m-tiles (rows 0..15, 16..31).
    // B-frags (global Wt, L2-resident) loaded once per (nt,ks), reused across both m-tiles.
    int col = lane & 15;
    int quad = lane >> 4;
    int f0 = wv * 32;

    f32x4 acc[2][2];
    acc[0][0] = (f32x4){0.f, 0.f, 0.f, 0.f};
    acc[0][1] = (f32x4){0.f, 0.f, 0.f, 0.f};
    acc[1][0] = (f32x4){0.f, 0.f, 0.f, 0.f};
    acc[1][1] = (f32x4){0.f, 0.f, 0.f, 0.f};

    const unsigned short* z0 = &zt[(col) * ZP + quad * 8];
    const unsigned short* z1 = &zt[(16 + col) * ZP + quad * 8];
    const unsigned short* wrow = &Wt[(size_t)(f0 + col) * 256 + quad * 8];

    #pragma unroll
    for (int ks = 0; ks < 8; ks++){
        bf16x8 b0 = *(const bf16x8*)&wrow[ks * 32];
        bf16x8 b1 = *(const bf16x8*)&wrow[16 * 256 + ks * 32];
        bf16x8 a0 = *(const bf16x8*)&z0[ks * 32];
        bf16x8 a1 = *(const bf16x8*)&z1[ks * 32];
        acc[0][0] = __builtin_amdgcn_mfma_f32_16x16x32_bf16(a0, b0, acc[0][0], 0, 0, 0);
        acc[0][1] = __builtin_amdgcn_mfma_f32_16x16x32_bf16(a0, b1, acc[0][1], 0, 0, 0);
        acc[1][0] = __builtin_amdgcn_mfma_f32_16x16x32_bf16(a1, b0, acc[1][0], 0, 0, 0);
        acc[1][1] = __builtin_amdgcn_mfma_f32_16x16x32_bf16(a1, b1, acc[1][1], 0, 0, 0);
    }

    __syncthreads();   // all waves done reading zt (A-frags)

    // write y = leaky(acc + b) into zt as f32 (pitch 132 floats = 528 B)
    float* zf = (float*)zt;
    #pragma unroll
    for (int nt = 0; nt < 2; nt++){
        int feat = f0 + nt * 16 + col;
        float bb_ = b[feat];
        #pragma unroll
        for (int mt = 0; mt < 2; mt++){
            #pragma unroll
            for (int r = 0; r < 4; r++){
                int row = mt * 16 + quad * 4 + r;
                zf[row * 132 + feat] = leaky(acc[mt][nt][r] + bb_);
            }
        }
    }
    __syncthreads();

    // coalesced epilogue: 1024 float4 slots = 32 rows x 32 quads; 256 threads x 4
    #pragma unroll
    for (int j = 0; j < 4; j++){
        int idx = j * 256 + tid;
        int row = idx >> 5;               // 0..31
        int q = idx & 31;                 // feats 4q..4q+3
        int node = nb + row;
        if (node < N_NODES){
            float4 y = *(float4*)&zf[row * 132 + 4 * q];
            if (add_skip){
                float4 hv = *(const float4*)&hin[(size_t)node * D + 4 * q];
                y.x += hv.x; y.y += hv.y; y.z += hv.z; y.w += hv.w;
            }
            *(float4*)&hout[(size_t)node * D + 4 * q] = y;
            if (write_hb){
                ushort4 rb;
                rb.x = f2bf(y.x); rb.y = f2bf(y.y); rb.z = f2bf(y.z); rb.w = f2bf(y.w);
                *(ushort4*)&hbout[(size_t)node * D + 4 * q] = rb;
            }
        }
    }
}

// ---------------- global max-pool per graph (batch sorted, int32) ----------------
__global__ __launch_bounds__(256) void k_pool(const float* __restrict__ h, const int* __restrict__ batch,
                                              unsigned* __restrict__ xg){
    __shared__ unsigned lmax[2 * D];
    int tid = threadIdx.x;
    lmax[tid] = 0u;
    __syncthreads();

    int n0 = blockIdx.x * PBLK;
    int g0 = batch[n0];
    int q = tid & 31;
    int s = tid >> 5;
    int i0 = n0 + s * PSL;
    int i1 = min(i0 + PSL, N_NODES);

    if (i0 < N_NODES){
        const float NEG = -INFINITY;
        float4 m = make_float4(NEG, NEG, NEG, NEG);
        int curg = batch[i0];
        int i = i0;
        for (; i + 2 <= i1; i += 2){
            int ga = batch[i];
            int gb = batch[i + 1];
            float4 va = *(const float4*)&h[(size_t)i * D + 4 * q];
            float4 vb = *(const float4*)&h[(size_t)(i + 1) * D + 4 * q];
            if (ga != curg){
                int rel = curg - g0;
                unsigned* dst = (rel < 2) ? &lmax[rel * D + 4 * q] : &xg[curg * D + 4 * q];
                atomicMax(dst + 0, fenc(m.x)); atomicMax(dst + 1, fenc(m.y));
                atomicMax(dst + 2, fenc(m.z)); atomicMax(dst + 3, fenc(m.w));
                curg = ga; m = make_float4(NEG, NEG, NEG, NEG);
            }
            m = max4(m, va);
            if (gb != curg){
                int rel = curg - g0;
                unsigned* dst = (rel < 2) ? &lmax[rel * D + 4 * q] : &xg[curg * D + 4 * q];
                atomicMax(dst + 0, fenc(m.x)); atomicMax(dst + 1, fenc(m.y));
                atomicMax(dst + 2, fenc(m.z)); atomicMax(dst + 3, fenc(m.w));
                curg = gb; m = make_float4(NEG, NEG, NEG, NEG);
            }
            m = max4(m, vb);
        }
        if (i < i1){
            int ga = batch[i];
            float4 va = *(const float4*)&h[(size_t)i * D + 4 * q];
            if (ga != curg){
                int rel = curg - g0;
                unsigned* dst = (rel < 2) ? &lmax[rel * D + 4 * q] : &xg[curg * D + 4 * q];
                atomicMax(dst + 0, fenc(m.x)); atomicMax(dst + 1, fenc(m.y));
                atomicMax(dst + 2, fenc(m.z)); atomicMax(dst + 3, fenc(m.w));
                curg = ga; m = make_float4(NEG, NEG, NEG, NEG);
            }
            m = max4(m, va);
        }
        {
            int rel = curg - g0;
            unsigned* dst = (rel < 2) ? &lmax[rel * D + 4 * q] : &xg[curg * D + 4 * q];
            atomicMax(dst + 0, fenc(m.x)); atomicMax(dst + 1, fenc(m.y));
            atomicMax(dst + 2, fenc(m.z)); atomicMax(dst + 3, fenc(m.w));
        }
    }
    __syncthreads();

    if (tid < D){
        unsigned e = lmax[tid];
        if (e) atomicMax(&xg[g0 * D + tid], e);
    } else {
        int f = tid - D;
        int g1 = g0 + 1;
        if (g1 < N_GRAPHS){
            unsigned e = lmax[D + f];
            if (e) atomicMax(&xg[g1 * D + f], e);
        }
    }
}

// ---------------- head: leaky(xg @ wg[:128] + bg) ----------------
__global__ __launch_bounds__(256) void k_final(const unsigned* __restrict__ xg_enc, const float* __restrict__ wg,
                                               const float* __restrict__ bg, float* __restrict__ out){
    __shared__ float xs[N_GRAPHS * D];
    int tid = threadIdx.x;
    for (int i = tid; i < N_GRAPHS * D; i += 256){
        unsigned e = xg_enc[i];
        xs[i] = (e == 0u) ? 0.f : fdec(e);
    }
    __syncthreads();
    int g = tid >> 4;
    int j0 = (tid & 15) * 8;
    float acc[8];
    #pragma unroll
    for (int j = 0; j < 8; j++) acc[j] = 0.f;
    for (int k = 0; k < D; k++){
        float xv = xs[g * D + k];
        const float* wr = &wg[(size_t)k * D + j0];
        #pragma unroll
        for (int j = 0; j < 8; j++) acc[j] = fmaf(xv, wr[j], acc[j]);
    }
    float* orow = &out[(size_t)N_NODES * D + g * D + j0];
    #pragma unroll
    for (int j = 0; j < 8; j++) orow[j] = leaky(acc[j] + bg[j0 + j]);
}

extern "C" void kernel_launch(void* const* d_in, const int* in_sizes, int n_in,
                              void* d_out, int out_size, void* d_ws, size_t ws_size,
                              hipStream_t stream){
    const float* x = (const float*)d_in[0];
    const int* eidx  = (const int*)d_in[1];   // harness converts integer inputs to int32
    const int* batch = (const int*)d_in[2];
    const float* w[4]  = {(const float*)d_in[4], (const float*)d_in[6], (const float*)d_in[8], (const float*)d_in[10]};
    const float* bb[4] = {(const float*)d_in[5], (const float*)d_in[7], (const float*)d_in[9], (const float*)d_in[11]};
    const float* wg = (const float*)d_in[12];
    const float* bg = (const float*)d_in[13];
    const int* esrc = eidx;
    const int* edst = eidx + N_EDGES;

    // workspace layout: padded deg (3.2MB) + xg + Wt + ELL (6.4MB) + hb0 (+hb1 if ping-pong fits)
    char* ws = (char*)d_ws;
    int* deg    = (int*)ws;       ws += 50048 * DEGP * 4;
    unsigned* xg_enc = (unsigned*)ws; ws += N_GRAPHS * D * 4;   // contiguous with deg for k_zero
    unsigned short* Wt = (unsigned short*)ws; ws += 4 * 2 * D * D * 2;  // 4 layers, [n][k] bf16
    unsigned short* ell = (unsigned short*)ws; ws += (size_t)N_NODES * ESTR * 2;
    unsigned short* hb0 = (unsigned short*)(((uintptr_t)ws + 255) & ~(uintptr_t)255);
    unsigned short* hb1 = hb0 + HB_ELEMS;
    size_t need_pp = (size_t)((char*)(hb1 + HB_ELEMS) - (char*)d_ws);
    int pp = (ws_size >= need_pp);     // ping-pong shadow if workspace allows (deterministic per run)
    float* h = (float*)d_out;          // f32 h lives in the output buffer (fully written by step 0)

    k_zero  <<<(50048 * DEGP + N_GRAPHS * D + 255) / 256, 256, 0, stream>>>((unsigned*)deg);
    k_pre   <<<6250, 256, 0, stream>>>(x, hb0, w[0], w[1], w[2], w[3], Wt, esrc, edst, deg, ell);
    k_padell<<<196, 256, 0, stream>>>(deg, ell);

    unsigned short* cur = hb0;
    unsigned short* nxt = pp ? hb1 : hb0;
    for (int s = 0; s < 4; s++){
        int wb = pp && (s < 3);        // ping-pong: write next shadow in-kernel (separate buffer)
        k_step<<<(N_NODES + TN - 1) / TN, 256, 0, stream>>>(h, cur, ell, deg,
                                                        Wt + (size_t)s * 2 * D * D, bb[s], h, nxt,
                                                        s > 0, wb);
        if (!pp && s < 3)              // fallback: refresh single shadow in a separate launch
            k_cvt<<<6250, 256, 0, stream>>>(h, hb0);
        if (pp){ unsigned short* t = cur; cur = nxt; nxt = t; }
    }

    k_pool <<<(N_NODES + PBLK - 1) / PBLK, 256, 0, stream>>>(h, batch, xg_enc);
    k_final<<<1, 256, 0, stream>>>(xg_enc, wg, bg, (float*)d_out);
}